// Round 16
// baseline (196.711 us; speedup 1.0000x reference)
//
#include <hip/hip_runtime.h>
#include <hip/hip_bf16.h>

using bf16 = __hip_bfloat16;
typedef __attribute__((ext_vector_type(8))) __bf16 bf16x8;
typedef __attribute__((ext_vector_type(4))) float f32x4;
typedef __attribute__((ext_vector_type(16))) float f32x16;
typedef __attribute__((ext_vector_type(4))) unsigned u32x4;

#define MFMA16(a, b, c) __builtin_amdgcn_mfma_f32_16x16x32_bf16((a), (b), (c), 0, 0, 0)
#define MFMA32(a, b, c) __builtin_amdgcn_mfma_f32_32x32x16_bf16((a), (b), (c), 0, 0, 0)

#define WAITV4 asm volatile("s_waitcnt vmcnt(4)" ::: "memory")
#define WAITV0 asm volatile("s_waitcnt vmcnt(0)" ::: "memory")
#define WAITL0 asm volatile("s_waitcnt lgkmcnt(0)" ::: "memory")
#define BAR    __builtin_amdgcn_s_barrier()
#define SCHED0 __builtin_amdgcn_sched_barrier(0)

static __device__ __forceinline__ void gload_lds16(const bf16* g, bf16* l) {
    __builtin_amdgcn_global_load_lds(
        (__attribute__((address_space(1))) void*)(bf16*)(g),
        (__attribute__((address_space(3))) void*)(l), 16, 0, 0);
}

static __device__ __forceinline__ unsigned cvtpk(float lo, float hi) {
    unsigned r;
    asm("v_cvt_pk_bf16_f32 %0, %1, %2" : "=v"(r) : "v"(lo), "v"(hi));
    return r;
}

// ---------------------------------------------------------------- convert (all 3 inputs, one launch)
__global__ void cvt_all(const float* __restrict__ x, const float* __restrict__ wq,
                        const float* __restrict__ wo,
                        bf16* __restrict__ xb, bf16* __restrict__ wqb, bf16* __restrict__ wob) {
    int b = blockIdx.x;
    const float* src;
    bf16* dst;
    long i;
    if (b < 8192)       { src = x;  dst = xb;  i = (long)b * 256 + threadIdx.x; }
    else if (b < 11264) { src = wq; dst = wqb; i = (long)(b - 8192) * 256 + threadIdx.x; }
    else                { src = wo; dst = wob; i = (long)(b - 11264) * 256 + threadIdx.x; }
    float4 v = ((const float4*)src)[i];
    bf16 t[4];
    t[0] = __float2bfloat16(v.x);
    t[1] = __float2bfloat16(v.y);
    t[2] = __float2bfloat16(v.z);
    t[3] = __float2bfloat16(v.w);
    *(uint2*)(dst + 4l * i) = *(uint2*)t;
}

// ---------------------------------------------------------------- shared GEMM pieces (16x16 MFMA, proven)
#define GEMM_STAGE(AB, BB, K0)                                             \
    do {                                                                   \
        gload_lds16(Ab + (long)srow * K + (K0) + scol, (AB) + t * 8);      \
        gload_lds16(Ab + (long)(srow + 64) * K + (K0) + scol, (AB) + 2048 + t * 8); \
        gload_lds16(Bb + (long)srow * K + (K0) + scol, (BB) + t * 8);      \
        gload_lds16(Bb + (long)(srow + 64) * K + (K0) + scol, (BB) + 2048 + t * 8); \
    } while (0)

#define GEMM_COMPUTE(AB, BB)                                               \
    do {                                                                   \
        bf16x8 af[4], bfv[4];                                              \
        _Pragma("unroll") for (int mi4 = 0; mi4 < 4; mi4++)                \
            af[mi4] = *(const bf16x8*)((AB) + (wm * 64 + mi4 * 16 + r) * 32 + q * 8); \
        _Pragma("unroll") for (int ni4 = 0; ni4 < 4; ni4++)                \
            bfv[ni4] = *(const bf16x8*)((BB) + (wn * 64 + ni4 * 16 + r) * 32 + q * 8); \
        __builtin_amdgcn_s_setprio(1);                                     \
        _Pragma("unroll") for (int mi4 = 0; mi4 < 4; mi4++)                \
            _Pragma("unroll") for (int ni4 = 0; ni4 < 4; ni4++)            \
                acc[mi4][ni4] = MFMA16(af[mi4], bfv[ni4], acc[mi4][ni4]);  \
        __builtin_amdgcn_s_setprio(0);                                     \
    } while (0)

#define GEMM_MAIN_LOOP                                                     \
    GEMM_STAGE(A0, B0, 0);                                                 \
    GEMM_STAGE(A1, B1, 32);                                                \
    for (int k0 = 0; k0 < K - 64; k0 += 64) {                              \
        WAITV4; BAR; SCHED0;                                               \
        GEMM_COMPUTE(A0, B0);                                              \
        WAITL0; BAR; SCHED0;                                               \
        GEMM_STAGE(A0, B0, k0 + 64);                                       \
        WAITV4; BAR; SCHED0;                                               \
        GEMM_COMPUTE(A1, B1);                                              \
        WAITL0; BAR; SCHED0;                                               \
        if (k0 + 96 < K) GEMM_STAGE(A1, B1, k0 + 96);                      \
    }                                                                      \
    WAITV4; BAR; SCHED0;                                                   \
    GEMM_COMPUTE(A0, B0);                                                  \
    WAITV0; BAR; SCHED0;                                                   \
    GEMM_COMPUTE(A1, B1);

// ---------------------------------------------------------------- GEMM1: qkv = x @ Wqkv^T + b, scatter to Q,K,V^T
__global__ void gemm_qkv(const bf16* __restrict__ A, const bf16* __restrict__ B,
                         const float* __restrict__ bias,
                         bf16* __restrict__ Qo, bf16* __restrict__ Ko, bf16* __restrict__ Vt) {
    const int K = 1024;
    __shared__ bf16 smem[16384];
    bf16* A0 = smem;
    bf16* B0 = smem + 4096;
    bf16* A1 = smem + 8192;
    bf16* B1 = smem + 12288;
    int t = threadIdx.x;
    int lane = t & 63;
    int wave = t >> 6;
    int wm = wave >> 1, wn = wave & 1;
    int r = lane & 15, q = lane >> 4;
    int lin = blockIdx.x;
    int xcd = lin & 7, rr_ = lin >> 3;
    int mi = xcd * 8 + (rr_ & 7);
    int ni = rr_ >> 3;
    long m0 = (long)mi * 128;
    long n0 = (long)ni * 128;
    const bf16* Ab = A + m0 * K;
    const bf16* Bb = B + n0 * K;

    f32x4 acc[4][4] = {};

    int srow = t >> 2;
    int scol = (t & 3) << 3;

    GEMM_MAIN_LOOP

#pragma unroll
    for (int ni4 = 0; ni4 < 4; ni4++) {
        int n = (int)n0 + wn * 64 + ni4 * 16 + r;
        float bn = bias[n];
        int h = n / 192;
        int rem = n % 192;
        int part = rem >> 6;
        int d = rem & 63;
#pragma unroll
        for (int mi4 = 0; mi4 < 4; mi4++) {
#pragma unroll
            for (int rr = 0; rr < 4; rr++) {
                int m = (int)m0 + wm * 64 + mi4 * 16 + q * 4 + rr;
                int b = m >> 11;
                int row = m & 2047;
                long bh = b * 16 + h;
                bf16 bv = __float2bfloat16(acc[mi4][ni4][rr] + bn);
                if (part == 0)      Qo[(bh * 2048 + row) * 64 + d] = bv;
                else if (part == 1) Ko[(bh * 2048 + row) * 64 + d] = bv;
                else                Vt[(bh * 64 + d) * 2048 + row] = bv;
            }
        }
    }
}

// ---------------------------------------------------------------- attention
// 8 waves x 64 q (2 q-blocks/wave, K/V frags SHARED across q-blocks: 16 LDS
// reads feed 32 MFMAs). 512 q/block; grid 256 = 1 block/CU. KVBLK=64 dbuf via
// global_load_lds. Swapped QK^T, in-reg P, O^T accum, defer-max.

#define PACK8(S, OFF, OUTV) { \
    unsigned A0_ = cvtpk(S[OFF+0], S[OFF+1]); \
    unsigned B0_ = cvtpk(S[OFF+4], S[OFF+5]); \
    unsigned A1_ = cvtpk(S[OFF+2], S[OFF+3]); \
    unsigned B1_ = cvtpk(S[OFF+6], S[OFF+7]); \
    asm("v_permlane32_swap_b32 %0, %1" : "+v"(A0_), "+v"(B0_)); \
    asm("v_permlane32_swap_b32 %0, %1" : "+v"(A1_), "+v"(B1_)); \
    u32x4 W; W.x = A0_; W.y = A1_; W.z = B0_; W.w = B1_; \
    OUTV = __builtin_bit_cast(bf16x8, W); }

// softmax + P-pack for one q-block (verbatim r9 math)
#define SMAXP(SA, SB, O0, O1, MV, LV, PF0, PF1, PF2, PF3) do { \
    float x0 = fmaxf(fmaxf(SA[0], SA[1]), fmaxf(SA[2], SA[3])); \
    float x1 = fmaxf(fmaxf(SA[4], SA[5]), fmaxf(SA[6], SA[7])); \
    float x2 = fmaxf(fmaxf(SA[8], SA[9]), fmaxf(SA[10], SA[11])); \
    float x3 = fmaxf(fmaxf(SA[12], SA[13]), fmaxf(SA[14], SA[15])); \
    float y0 = fmaxf(fmaxf(SB[0], SB[1]), fmaxf(SB[2], SB[3])); \
    float y1 = fmaxf(fmaxf(SB[4], SB[5]), fmaxf(SB[6], SB[7])); \
    float y2 = fmaxf(fmaxf(SB[8], SB[9]), fmaxf(SB[10], SB[11])); \
    float y3 = fmaxf(fmaxf(SB[12], SB[13]), fmaxf(SB[14], SB[15])); \
    float pm = fmaxf(fmaxf(fmaxf(x0, x1), fmaxf(x2, x3)), \
                     fmaxf(fmaxf(y0, y1), fmaxf(y2, y3))); \
    pm = fmaxf(pm, __shfl_xor(pm, 32)); \
    bool resc = !__all(pm <= MV + 8.0f); \
    if (resc) { \
        float mn = fmaxf(MV, pm); \
        float al = __builtin_amdgcn_exp2f((MV - mn) * C1); \
        MV = mn; \
        LV *= al; \
        _Pragma("unroll") for (int e = 0; e < 16; ++e) { O0[e] *= al; O1[e] *= al; } \
    } \
    float mc = MV * C1; \
    float ts = 0.f; \
    _Pragma("unroll") for (int e = 0; e < 16; ++e) { float p = __builtin_amdgcn_exp2f(SA[e] * C1 - mc); SA[e] = p; ts += p; } \
    _Pragma("unroll") for (int e = 0; e < 16; ++e) { float p = __builtin_amdgcn_exp2f(SB[e] * C1 - mc); SB[e] = p; ts += p; } \
    ts += __shfl_xor(ts, 32); \
    LV += ts; \
    PACK8(SA, 0, PF0); PACK8(SA, 8, PF1); PACK8(SB, 0, PF2); PACK8(SB, 8, PF3); \
} while (0)

#define COMPUTE2(KB, VB) do { \
    f32x16 sA0 = {}, sB0 = {}, sA1 = {}, sB1 = {}; \
    __builtin_amdgcn_s_setprio(1); \
    { \
        bf16x8 kA, kB; \
        kA = *(const bf16x8*)(KB + (0 * 64 + lane) * 8); \
        kB = *(const bf16x8*)(KB + (256 + 0 * 64 + lane) * 8); \
        sA0 = MFMA32(kA, qfA0, sA0);  sB0 = MFMA32(kB, qfA0, sB0); \
        sA1 = MFMA32(kA, qfB0, sA1);  sB1 = MFMA32(kB, qfB0, sB1); \
        kA = *(const bf16x8*)(KB + (1 * 64 + lane) * 8); \
        kB = *(const bf16x8*)(KB + (256 + 1 * 64 + lane) * 8); \
        sA0 = MFMA32(kA, qfA1, sA0);  sB0 = MFMA32(kB, qfA1, sB0); \
        sA1 = MFMA32(kA, qfB1, sA1);  sB1 = MFMA32(kB, qfB1, sB1); \
        kA = *(const bf16x8*)(KB + (2 * 64 + lane) * 8); \
        kB = *(const bf16x8*)(KB + (256 + 2 * 64 + lane) * 8); \
        sA0 = MFMA32(kA, qfA2, sA0);  sB0 = MFMA32(kB, qfA2, sB0); \
        sA1 = MFMA32(kA, qfB2, sA1);  sB1 = MFMA32(kB, qfB2, sB1); \
        kA = *(const bf16x8*)(KB + (3 * 64 + lane) * 8); \
        kB = *(const bf16x8*)(KB + (256 + 3 * 64 + lane) * 8); \
        sA0 = MFMA32(kA, qfA3, sA0);  sB0 = MFMA32(kB, qfA3, sB0); \
        sA1 = MFMA32(kA, qfB3, sA1);  sB1 = MFMA32(kB, qfB3, sB1); \
    } \
    __builtin_amdgcn_s_setprio(0); \
    bf16x8 p00, p01, p02, p03, p10, p11, p12, p13; \
    SMAXP(sA0, sB0, o00, o01, mv0, lv0, p00, p01, p02, p03); \
    SMAXP(sA1, sB1, o10, o11, mv1, lv1, p10, p11, p12, p13); \
    __builtin_amdgcn_s_setprio(1); \
    { \
        bf16x8 vA, vB; \
        vA = *(const bf16x8*)(VB + (0 * 64 + lane) * 8); \
        vB = *(const bf16x8*)(VB + (256 + 0 * 64 + lane) * 8); \
        o00 = MFMA32(vA, p00, o00);  o01 = MFMA32(vB, p00, o01); \
        o10 = MFMA32(vA, p10, o10);  o11 = MFMA32(vB, p10, o11); \
        vA = *(const bf16x8*)(VB + (1 * 64 + lane) * 8); \
        vB = *(const bf16x8*)(VB + (256 + 1 * 64 + lane) * 8); \
        o00 = MFMA32(vA, p01, o00);  o01 = MFMA32(vB, p01, o01); \
        o10 = MFMA32(vA, p11, o10);  o11 = MFMA32(vB, p11, o11); \
        vA = *(const bf16x8*)(VB + (2 * 64 + lane) * 8); \
        vB = *(const bf16x8*)(VB + (256 + 2 * 64 + lane) * 8); \
        o00 = MFMA32(vA, p02, o00);  o01 = MFMA32(vB, p02, o01); \
        o10 = MFMA32(vA, p12, o10);  o11 = MFMA32(vB, p12, o11); \
        vA = *(const bf16x8*)(VB + (3 * 64 + lane) * 8); \
        vB = *(const bf16x8*)(VB + (256 + 3 * 64 + lane) * 8); \
        o00 = MFMA32(vA, p03, o00);  o01 = MFMA32(vB, p03, o01); \
        o10 = MFMA32(vA, p13, o10);  o11 = MFMA32(vB, p13, o11); \
    } \
    __builtin_amdgcn_s_setprio(0); \
} while (0)

#define EPI(O0v, O1v, LVv, QBOFF) { \
    __syncthreads(); \
    float il = 1.f / LVv; \
    char* wbase = (char*)smem + wave * 4096 + l31 * 128; \
    _Pragma("unroll") for (int j = 0; j < 4; ++j) { \
        unsigned wlo = cvtpk(O0v[4 * j] * il, O0v[4 * j + 1] * il); \
        unsigned whi = cvtpk(O0v[4 * j + 2] * il, O0v[4 * j + 3] * il); \
        int b8 = 2 * j + hi; int b8s = b8 ^ ((l31 & 7) << 1); \
        uint2 val; val.x = wlo; val.y = whi; \
        *(uint2*)(wbase + b8s * 8) = val; } \
    _Pragma("unroll") for (int j = 0; j < 4; ++j) { \
        unsigned wlo = cvtpk(O1v[4 * j] * il, O1v[4 * j + 1] * il); \
        unsigned whi = cvtpk(O1v[4 * j + 2] * il, O1v[4 * j + 3] * il); \
        int b8 = 8 + 2 * j + hi; int b8s = b8 ^ ((l31 & 7) << 1); \
        uint2 val; val.x = wlo; val.y = whi; \
        *(uint2*)(wbase + b8s * 8) = val; } \
    __syncthreads(); \
    { int rid = t >> 1, hf = t & 1; \
      int wv = rid >> 5, qq = rid & 31; \
      long orow = (long)qt * 512 + wv * 64 + (QBOFF) + qq; \
      const char* rbase = (const char*)smem + wv * 4096 + qq * 128; \
      bf16* dst = AO + (bb * 2048 + orow) * 1024 + hh * 64 + hf * 32; \
      _Pragma("unroll") for (int k = 0; k < 4; ++k) { \
          int b8 = hf * 8 + 2 * k; int b8s = b8 ^ ((qq & 7) << 1); \
          int4 v = *(const int4*)(rbase + b8s * 8); \
          *(int4*)(dst + k * 8) = v; } } }

__global__ __launch_bounds__(512, 2) void attn_fwd(const bf16* __restrict__ Q,
                                                   const bf16* __restrict__ Kg,
                                                   const bf16* __restrict__ Vt,
                                                   bf16* __restrict__ AO) {
    __shared__ bf16 smem[16384];   // [K0 4096][V0 4096][K1 4096][V1 4096]
    bf16* K0 = smem;
    bf16* V0 = smem + 4096;
    bf16* K1 = smem + 8192;
    bf16* V1 = smem + 12288;
    const int t = threadIdx.x;
    const int lane = t & 63, wave = t >> 6;
    const int l31 = lane & 31, hi = lane >> 5;
    // 256 blocks; xcd = bid&7 owns 8 bh; 4 q-tiles of 512 q per bh
    const int bid = blockIdx.x;
    const int xcd = bid & 7, idx = bid >> 3;      // idx 0..31
    const int bh = xcd * 8 + (idx >> 2);
    const int qt = idx & 3;
    const float C1 = 0.18033688011112042f;   // log2(e)/sqrt(64)

    // Q fragments: 2 q-blocks (A: +0..31, B: +32..63), 4 k-chunks each
    bf16x8 qfA0, qfA1, qfA2, qfA3, qfB0, qfB1, qfB2, qfB3;
    {
        const bf16* Qb = Q + ((long)bh * 2048 + qt * 512 + wave * 64 + l31) * 64 + hi * 8;
        qfA0 = *(const bf16x8*)(Qb + 0);
        qfA1 = *(const bf16x8*)(Qb + 16);
        qfA2 = *(const bf16x8*)(Qb + 32);
        qfA3 = *(const bf16x8*)(Qb + 48);
        const bf16* Qb2 = Qb + 32 * 64;
        qfB0 = *(const bf16x8*)(Qb2 + 0);
        qfB1 = *(const bf16x8*)(Qb2 + 16);
        qfB2 = *(const bf16x8*)(Qb2 + 32);
        qfB3 = *(const bf16x8*)(Qb2 + 48);
    }

    const bf16* Kh = Kg + (long)bh * 2048 * 64;
    const bf16* Vh = Vt + (long)bh * 64 * 2048;

    const int sr = ((t >> 8) << 5) + (t & 31);          // 0..63
    const int sc = ((t >> 6) & 3) * 16 + ((t >> 5) & 1) * 8;

    f32x16 o00 = {}, o01 = {}, o10 = {}, o11 = {};
    float mv0 = -1e30f, mv1 = -1e30f, lv0 = 0.f, lv1 = 0.f;

    auto issue_stage = [&](bf16* Kb, bf16* Vb, int kv0) {
        gload_lds16(Kh + (long)(kv0 + sr) * 64 + sc, Kb + t * 8);
        gload_lds16(Vh + (long)sr * 2048 + kv0 + sc, Vb + t * 8);
    };

    issue_stage(K0, V0, 0);
    __syncthreads();                         // K0/V0 ready

    for (int kv0 = 0;; kv0 += 128) {
        issue_stage(K1, V1, kv0 + 64);       // prefetch tile B
        COMPUTE2(K0, V0);                    // tile A, both q-blocks
        __syncthreads();                     // K1 ready, K0 free
        if (kv0 + 128 < 2048) issue_stage(K0, V0, kv0 + 128);
        COMPUTE2(K1, V1);                    // tile B
        if (kv0 + 128 >= 2048) break;
        __syncthreads();                     // K0' ready, K1 free
    }

    // ---- epilogue: O^T -> LDS transpose -> coalesced global stores (per qb)
    long bb = bh >> 4, hh = bh & 15;
    EPI(o00, o01, lv0, 0);
    EPI(o10, o11, lv1, 32);
}

// ---------------------------------------------------------------- GEMM2: out = AO @ Wo^T + bo (fp32 out, 16x16 MFMA)
__global__ void gemm_out(const bf16* __restrict__ A, const bf16* __restrict__ B,
                         const float* __restrict__ bias, float* __restrict__ C) {
    const int K = 1024, N = 1024;
    __shared__ bf16 smem[16384];
    bf16* A0 = smem;
    bf16* B0 = smem + 4096;
    bf16* A1 = smem + 8192;
    bf16* B1 = smem + 12288;
    int t = threadIdx.x;
    int lane = t & 63;
    int wave = t >> 6;
    int wm = wave >> 1, wn = wave & 1;
    int r = lane & 15, q = lane >> 4;
    int lin = blockIdx.x;
    int xcd = lin & 7, rr_ = lin >> 3;
    int mi = xcd * 8 + (rr_ & 7);
    int ni = rr_ >> 3;
    long m0 = (long)mi * 128;
    long n0 = (long)ni * 128;
    const bf16* Ab = A + m0 * K;
    const bf16* Bb = B + n0 * K;

    f32x4 acc[4][4] = {};

    int srow = t >> 2;
    int scol = (t & 3) << 3;

    GEMM_MAIN_LOOP

#pragma unroll
    for (int ni4 = 0; ni4 < 4; ni4++) {
        int n = (int)n0 + wn * 64 + ni4 * 16 + r;
        float bn = bias[n];
#pragma unroll
        for (int mi4 = 0; mi4 < 4; mi4++) {
#pragma unroll
            for (int rr = 0; rr < 4; rr++) {
                long m = m0 + wm * 64 + mi4 * 16 + q * 4 + rr;
                C[m * N + n] = acc[mi4][ni4][rr] + bn;
            }
        }
    }
}

// ---------------------------------------------------------------- launch
extern "C" void kernel_launch(void* const* d_in, const int* in_sizes, int n_in,
                              void* d_out, int out_size, void* d_ws, size_t ws_size,
                              hipStream_t stream) {
    const float* x    = (const float*)d_in[0];
    const float* Wqkv = (const float*)d_in[1];
    const float* bqkv = (const float*)d_in[2];
    const float* Wo   = (const float*)d_in[3];
    const float* bo   = (const float*)d_in[4];
    float* out = (float*)d_out;

    char* ws = (char*)d_ws;
    bf16* Xb  = (bf16*)(ws + 0);
    bf16* Wqb = (bf16*)(ws + 16777216);
    bf16* Wob = (bf16*)(ws + 23068672);
    bf16* Qb  = (bf16*)(ws + 25165824);
    bf16* Kb  = (bf16*)(ws + 41943040);
    bf16* Vtb = (bf16*)(ws + 58720256);
    bf16* AOb = (bf16*)(ws + 75497472);

    cvt_all<<<12288, 256, 0, stream>>>(x, Wqkv, Wo, Xb, Wqb, Wob);

    gemm_qkv<<<1536, 256, 0, stream>>>(Xb, Wqb, bqkv, Qb, Kb, Vtb);
    attn_fwd<<<256, 512, 0, stream>>>(Qb, Kb, Vtb, AOb);
    gemm_out<<<512, 256, 0, stream>>>(AOb, Wob, bo, out);
}

// Round 17
// 192.218 us; speedup vs baseline: 1.0234x; 1.0234x over previous
//
#include <hip/hip_runtime.h>
#include <hip/hip_bf16.h>

using bf16 = __hip_bfloat16;
typedef __attribute__((ext_vector_type(8))) __bf16 bf16x8;
typedef __attribute__((ext_vector_type(4))) float f32x4;
typedef __attribute__((ext_vector_type(16))) float f32x16;
typedef __attribute__((ext_vector_type(4))) unsigned u32x4;

#define MFMA16(a, b, c) __builtin_amdgcn_mfma_f32_16x16x32_bf16((a), (b), (c), 0, 0, 0)
#define MFMA32(a, b, c) __builtin_amdgcn_mfma_f32_32x32x16_bf16((a), (b), (c), 0, 0, 0)

#define WAITV4 asm volatile("s_waitcnt vmcnt(4)" ::: "memory")
#define WAITV0 asm volatile("s_waitcnt vmcnt(0)" ::: "memory")
#define WAITL0 asm volatile("s_waitcnt lgkmcnt(0)" ::: "memory")
#define BAR    __builtin_amdgcn_s_barrier()
#define SCHED0 __builtin_amdgcn_sched_barrier(0)

static __device__ __forceinline__ void gload_lds16(const bf16* g, bf16* l) {
    __builtin_amdgcn_global_load_lds(
        (__attribute__((address_space(1))) void*)(bf16*)(g),
        (__attribute__((address_space(3))) void*)(l), 16, 0, 0);
}

static __device__ __forceinline__ unsigned cvtpk(float lo, float hi) {
    unsigned r;
    asm("v_cvt_pk_bf16_f32 %0, %1, %2" : "=v"(r) : "v"(lo), "v"(hi));
    return r;
}

// ---------------------------------------------------------------- convert (all 3 inputs, one launch)
__global__ void cvt_all(const float* __restrict__ x, const float* __restrict__ wq,
                        const float* __restrict__ wo,
                        bf16* __restrict__ xb, bf16* __restrict__ wqb, bf16* __restrict__ wob) {
    int b = blockIdx.x;
    const float* src;
    bf16* dst;
    long i;
    if (b < 8192)       { src = x;  dst = xb;  i = (long)b * 256 + threadIdx.x; }
    else if (b < 11264) { src = wq; dst = wqb; i = (long)(b - 8192) * 256 + threadIdx.x; }
    else                { src = wo; dst = wob; i = (long)(b - 11264) * 256 + threadIdx.x; }
    float4 v = ((const float4*)src)[i];
    bf16 t[4];
    t[0] = __float2bfloat16(v.x);
    t[1] = __float2bfloat16(v.y);
    t[2] = __float2bfloat16(v.z);
    t[3] = __float2bfloat16(v.w);
    *(uint2*)(dst + 4l * i) = *(uint2*)t;
}

// ---------------------------------------------------------------- shared GEMM pieces (16x16 MFMA, proven)
#define GEMM_STAGE(AB, BB, K0)                                             \
    do {                                                                   \
        gload_lds16(Ab + (long)srow * K + (K0) + scol, (AB) + t * 8);      \
        gload_lds16(Ab + (long)(srow + 64) * K + (K0) + scol, (AB) + 2048 + t * 8); \
        gload_lds16(Bb + (long)srow * K + (K0) + scol, (BB) + t * 8);      \
        gload_lds16(Bb + (long)(srow + 64) * K + (K0) + scol, (BB) + 2048 + t * 8); \
    } while (0)

#define GEMM_COMPUTE(AB, BB)                                               \
    do {                                                                   \
        bf16x8 af[4], bfv[4];                                              \
        _Pragma("unroll") for (int mi4 = 0; mi4 < 4; mi4++)                \
            af[mi4] = *(const bf16x8*)((AB) + (wm * 64 + mi4 * 16 + r) * 32 + q * 8); \
        _Pragma("unroll") for (int ni4 = 0; ni4 < 4; ni4++)                \
            bfv[ni4] = *(const bf16x8*)((BB) + (wn * 64 + ni4 * 16 + r) * 32 + q * 8); \
        __builtin_amdgcn_s_setprio(1);                                     \
        _Pragma("unroll") for (int mi4 = 0; mi4 < 4; mi4++)                \
            _Pragma("unroll") for (int ni4 = 0; ni4 < 4; ni4++)            \
                acc[mi4][ni4] = MFMA16(af[mi4], bfv[ni4], acc[mi4][ni4]);  \
        __builtin_amdgcn_s_setprio(0);                                     \
    } while (0)

#define GEMM_MAIN_LOOP                                                     \
    GEMM_STAGE(A0, B0, 0);                                                 \
    GEMM_STAGE(A1, B1, 32);                                                \
    for (int k0 = 0; k0 < K - 64; k0 += 64) {                              \
        WAITV4; BAR; SCHED0;                                               \
        GEMM_COMPUTE(A0, B0);                                              \
        WAITL0; BAR; SCHED0;                                               \
        GEMM_STAGE(A0, B0, k0 + 64);                                       \
        WAITV4; BAR; SCHED0;                                               \
        GEMM_COMPUTE(A1, B1);                                              \
        WAITL0; BAR; SCHED0;                                               \
        if (k0 + 96 < K) GEMM_STAGE(A1, B1, k0 + 96);                      \
    }                                                                      \
    WAITV4; BAR; SCHED0;                                                   \
    GEMM_COMPUTE(A0, B0);                                                  \
    WAITV0; BAR; SCHED0;                                                   \
    GEMM_COMPUTE(A1, B1);

// ---------------------------------------------------------------- GEMM1: qkv = x @ Wqkv^T + b, scatter to Q,K,V^T
// Per wave the 64-col segment has uniform part p = (2*ni+wn)%3, head (2*ni+wn)/3.
// Q/K stored direct (line-dense); V segment routed through LDS transpose and
// stored as coalesced V^T rows (kills partial-line RMW write amplification).
__global__ void gemm_qkv(const bf16* __restrict__ A, const bf16* __restrict__ B,
                         const float* __restrict__ bias,
                         bf16* __restrict__ Qo, bf16* __restrict__ Ko, bf16* __restrict__ Vt) {
    const int K = 1024;
    __shared__ bf16 smem[16384];
    bf16* A0 = smem;
    bf16* B0 = smem + 4096;
    bf16* A1 = smem + 8192;
    bf16* B1 = smem + 12288;
    int t = threadIdx.x;
    int lane = t & 63;
    int wave = t >> 6;
    int wm = wave >> 1, wn = wave & 1;
    int r = lane & 15, q = lane >> 4;
    int lin = blockIdx.x;
    int xcd = lin & 7, rr_ = lin >> 3;
    int mi = xcd * 8 + (rr_ & 7);
    int ni = rr_ >> 3;
    long m0 = (long)mi * 128;
    long n0 = (long)ni * 128;
    const bf16* Ab = A + m0 * K;
    const bf16* Bb = B + n0 * K;

    f32x4 acc[4][4] = {};

    int srow = t >> 2;
    int scol = (t & 3) << 3;

    GEMM_MAIN_LOOP

    // ---- epilogue
    __syncthreads();                       // staging smem free for reuse
    bf16* vbuf = smem;                     // [d 0..63][m_local 0..127], stride 136
    int g64 = 2 * ni + wn;                 // this wave's 64-col segment id
    int pw = g64 % 3;                      // part (uniform per wave)
    int hw = g64 / 3;                      // head
#pragma unroll
    for (int ni4 = 0; ni4 < 4; ni4++) {
        int d = ni4 * 16 + r;              // segment-local col
        float bn = bias[(int)n0 + wn * 64 + d];
#pragma unroll
        for (int mi4 = 0; mi4 < 4; mi4++) {
#pragma unroll
            for (int rr = 0; rr < 4; rr++) {
                int ml = wm * 64 + mi4 * 16 + q * 4 + rr;     // m_local
                int m = (int)m0 + ml;
                bf16 bv = __float2bfloat16(acc[mi4][ni4][rr] + bn);
                if (pw == 0) {
                    int b = m >> 11; int row = m & 2047;
                    Qo[(((long)b * 16 + hw) * 2048 + row) * 64 + d] = bv;
                } else if (pw == 1) {
                    int b = m >> 11; int row = m & 2047;
                    Ko[(((long)b * 16 + hw) * 2048 + row) * 64 + d] = bv;
                } else {
                    vbuf[d * 136 + ml] = bv;
                }
            }
        }
    }
    __syncthreads();
    // cooperative coalesced V^T store (at most one part-2 segment per block)
    int vseg = ((2 * ni) % 3 == 2) ? 0 : (((2 * ni + 1) % 3 == 2) ? 1 : -1);
    if (vseg >= 0) {
        int hv = (2 * ni + vseg) / 3;
        int b = (int)(m0 >> 11);
        int row0 = (int)(m0 & 2047);
        long base = ((long)b * 16 + hv) * 64 * 2048;
#pragma unroll
        for (int c = 0; c < 4; ++c) {
            int u = c * 256 + t;           // 0..1023
            int d = u >> 4;                // 0..63
            int ch = u & 15;               // 0..15 (8 bf16 each)
            int4 v = *(const int4*)(vbuf + d * 136 + ch * 8);
            *(int4*)(Vt + base + (long)d * 2048 + row0 + ch * 8) = v;
        }
    }
}

// ---------------------------------------------------------------- attention (round-9 proven config, verbatim)
// 8 waves x 32 q = 256 q/block; KVBLK=64 double-buffered via global_load_lds.
// Swapped QK^T, in-register P (permlane32_swap), O^T accum, defer-max.

#define PACK8(S, OFF, OUTV) { \
    unsigned A0_ = cvtpk(S[OFF+0], S[OFF+1]); \
    unsigned B0_ = cvtpk(S[OFF+4], S[OFF+5]); \
    unsigned A1_ = cvtpk(S[OFF+2], S[OFF+3]); \
    unsigned B1_ = cvtpk(S[OFF+6], S[OFF+7]); \
    asm("v_permlane32_swap_b32 %0, %1" : "+v"(A0_), "+v"(B0_)); \
    asm("v_permlane32_swap_b32 %0, %1" : "+v"(A1_), "+v"(B1_)); \
    u32x4 W; W.x = A0_; W.y = A1_; W.z = B0_; W.w = B1_; \
    OUTV = __builtin_bit_cast(bf16x8, W); }

#define COMPUTE(KB, VB) do { \
    f32x16 sA = {}, sB = {}; \
    __builtin_amdgcn_s_setprio(1); \
    { \
        bf16x8 kA, kB; \
        kA = *(const bf16x8*)(KB + (0 * 64 + lane) * 8); \
        kB = *(const bf16x8*)(KB + (256 + 0 * 64 + lane) * 8); \
        sA = MFMA32(kA, qf0, sA);  sB = MFMA32(kB, qf0, sB); \
        kA = *(const bf16x8*)(KB + (1 * 64 + lane) * 8); \
        kB = *(const bf16x8*)(KB + (256 + 1 * 64 + lane) * 8); \
        sA = MFMA32(kA, qf1, sA);  sB = MFMA32(kB, qf1, sB); \
        kA = *(const bf16x8*)(KB + (2 * 64 + lane) * 8); \
        kB = *(const bf16x8*)(KB + (256 + 2 * 64 + lane) * 8); \
        sA = MFMA32(kA, qf2, sA);  sB = MFMA32(kB, qf2, sB); \
        kA = *(const bf16x8*)(KB + (3 * 64 + lane) * 8); \
        kB = *(const bf16x8*)(KB + (256 + 3 * 64 + lane) * 8); \
        sA = MFMA32(kA, qf3, sA);  sB = MFMA32(kB, qf3, sB); \
    } \
    __builtin_amdgcn_s_setprio(0); \
    float x0 = fmaxf(fmaxf(sA[0], sA[1]), fmaxf(sA[2], sA[3])); \
    float x1 = fmaxf(fmaxf(sA[4], sA[5]), fmaxf(sA[6], sA[7])); \
    float x2 = fmaxf(fmaxf(sA[8], sA[9]), fmaxf(sA[10], sA[11])); \
    float x3 = fmaxf(fmaxf(sA[12], sA[13]), fmaxf(sA[14], sA[15])); \
    float y0 = fmaxf(fmaxf(sB[0], sB[1]), fmaxf(sB[2], sB[3])); \
    float y1 = fmaxf(fmaxf(sB[4], sB[5]), fmaxf(sB[6], sB[7])); \
    float y2 = fmaxf(fmaxf(sB[8], sB[9]), fmaxf(sB[10], sB[11])); \
    float y3 = fmaxf(fmaxf(sB[12], sB[13]), fmaxf(sB[14], sB[15])); \
    float pm = fmaxf(fmaxf(fmaxf(x0, x1), fmaxf(x2, x3)), \
                     fmaxf(fmaxf(y0, y1), fmaxf(y2, y3))); \
    pm = fmaxf(pm, __shfl_xor(pm, 32)); \
    bool resc = !__all(pm <= mv + 8.0f); \
    if (resc) { \
        float mn = fmaxf(mv, pm); \
        float al = __builtin_amdgcn_exp2f((mv - mn) * C1); \
        mv = mn; \
        lv *= al; \
        _Pragma("unroll") for (int e = 0; e < 16; ++e) { o0[e] *= al; o1[e] *= al; } \
    } \
    float mc = mv * C1; \
    float ts = 0.f; \
    _Pragma("unroll") for (int e = 0; e < 16; ++e) { float p = __builtin_amdgcn_exp2f(sA[e] * C1 - mc); sA[e] = p; ts += p; } \
    _Pragma("unroll") for (int e = 0; e < 16; ++e) { float p = __builtin_amdgcn_exp2f(sB[e] * C1 - mc); sB[e] = p; ts += p; } \
    ts += __shfl_xor(ts, 32); \
    lv += ts; \
    bf16x8 pf0, pf1, pf2, pf3; \
    PACK8(sA, 0, pf0); PACK8(sA, 8, pf1); PACK8(sB, 0, pf2); PACK8(sB, 8, pf3); \
    __builtin_amdgcn_s_setprio(1); \
    { \
        bf16x8 vA, vB; \
        vA = *(const bf16x8*)(VB + (0 * 64 + lane) * 8); \
        vB = *(const bf16x8*)(VB + (256 + 0 * 64 + lane) * 8); \
        o0 = MFMA32(vA, pf0, o0);  o1 = MFMA32(vB, pf0, o1); \
        vA = *(const bf16x8*)(VB + (1 * 64 + lane) * 8); \
        vB = *(const bf16x8*)(VB + (256 + 1 * 64 + lane) * 8); \
        o0 = MFMA32(vA, pf1, o0);  o1 = MFMA32(vB, pf1, o1); \
        vA = *(const bf16x8*)(VB + (2 * 64 + lane) * 8); \
        vB = *(const bf16x8*)(VB + (256 + 2 * 64 + lane) * 8); \
        o0 = MFMA32(vA, pf2, o0);  o1 = MFMA32(vB, pf2, o1); \
        vA = *(const bf16x8*)(VB + (3 * 64 + lane) * 8); \
        vB = *(const bf16x8*)(VB + (256 + 3 * 64 + lane) * 8); \
        o0 = MFMA32(vA, pf3, o0);  o1 = MFMA32(vB, pf3, o1); \
    } \
    __builtin_amdgcn_s_setprio(0); \
} while (0)

__global__ __launch_bounds__(512, 4) void attn_fwd(const bf16* __restrict__ Q,
                                                   const bf16* __restrict__ Kg,
                                                   const bf16* __restrict__ Vt,
                                                   bf16* __restrict__ AO) {
    __shared__ bf16 smem[16384];   // [K0 4096][V0 4096][K1 4096][V1 4096]
    bf16* K0 = smem;
    bf16* V0 = smem + 4096;
    bf16* K1 = smem + 8192;
    bf16* V1 = smem + 12288;
    const int t = threadIdx.x;
    const int lane = t & 63, wave = t >> 6;
    const int l31 = lane & 31, hi = lane >> 5;
    // XCD swizzle: 512 blocks; xcd = bid&7 owns bh in [xcd*8, xcd*8+8)
    const int bid = blockIdx.x;
    const int xcd = bid & 7, idx = bid >> 3;
    const int bh = xcd * 8 + (idx >> 3);
    const int qt = idx & 7;
    const float C1 = 0.18033688011112042f;   // log2(e)/sqrt(64)

    bf16x8 qf0, qf1, qf2, qf3;
    {
        const bf16* Qb = Q + ((long)bh * 2048 + qt * 256 + wave * 32 + l31) * 64 + hi * 8;
        qf0 = *(const bf16x8*)(Qb + 0);
        qf1 = *(const bf16x8*)(Qb + 16);
        qf2 = *(const bf16x8*)(Qb + 32);
        qf3 = *(const bf16x8*)(Qb + 48);
    }

    const bf16* Kh = Kg + (long)bh * 2048 * 64;
    const bf16* Vh = Vt + (long)bh * 64 * 2048;

    const int sr = ((t >> 8) << 5) + (t & 31);          // 0..63
    const int sc = ((t >> 6) & 3) * 16 + ((t >> 5) & 1) * 8;

    f32x16 o0 = {}, o1 = {};
    float mv = -1e30f, lv = 0.f;

    auto issue_stage = [&](bf16* Kb, bf16* Vb, int kv0) {
        gload_lds16(Kh + (long)(kv0 + sr) * 64 + sc, Kb + t * 8);
        gload_lds16(Vh + (long)sr * 2048 + kv0 + sc, Vb + t * 8);
    };

    issue_stage(K0, V0, 0);
    __syncthreads();                         // K0/V0 ready

    for (int kv0 = 0;; kv0 += 128) {
        issue_stage(K1, V1, kv0 + 64);       // prefetch tile B
        COMPUTE(K0, V0);                     // tile A
        __syncthreads();                     // K1 ready, K0 free
        if (kv0 + 128 < 2048) issue_stage(K0, V0, kv0 + 128);
        COMPUTE(K1, V1);                     // tile B
        if (kv0 + 128 >= 2048) break;
        __syncthreads();                     // K0' ready, K1 free
    }

    // ---- epilogue: O^T -> LDS transpose -> coalesced global stores
    long bb = bh >> 4, hh = bh & 15;
    __syncthreads();
    float il = 1.f / lv;
    char* wbase = (char*)smem + wave * 4096 + l31 * 128;
#pragma unroll
    for (int j = 0; j < 4; ++j) {
        unsigned wlo = cvtpk(o0[4 * j] * il, o0[4 * j + 1] * il);
        unsigned whi = cvtpk(o0[4 * j + 2] * il, o0[4 * j + 3] * il);
        int b8 = 2 * j + hi;
        int b8s = b8 ^ ((l31 & 7) << 1);
        uint2 val; val.x = wlo; val.y = whi;
        *(uint2*)(wbase + b8s * 8) = val;
    }
#pragma unroll
    for (int j = 0; j < 4; ++j) {
        unsigned wlo = cvtpk(o1[4 * j] * il, o1[4 * j + 1] * il);
        unsigned whi = cvtpk(o1[4 * j + 2] * il, o1[4 * j + 3] * il);
        int b8 = 8 + 2 * j + hi;
        int b8s = b8 ^ ((l31 & 7) << 1);
        uint2 val; val.x = wlo; val.y = whi;
        *(uint2*)(wbase + b8s * 8) = val;
    }
    __syncthreads();
    {
        int rid = t >> 1, hf = t & 1;
        int wv = rid >> 5, qq = rid & 31;
        long orow = (long)qt * 256 + wv * 32 + qq;
        const char* rbase = (const char*)smem + wv * 4096 + qq * 128;
        bf16* dst = AO + (bb * 2048 + orow) * 1024 + hh * 64 + hf * 32;
#pragma unroll
        for (int k = 0; k < 4; ++k) {
            int b8 = hf * 8 + 2 * k;
            int b8s = b8 ^ ((qq & 7) << 1);
            int4 v = *(const int4*)(rbase + b8s * 8);
            *(int4*)(dst + k * 8) = v;
        }
    }
}

// ---------------------------------------------------------------- GEMM2: out = AO @ Wo^T + bo (fp32 out, 16x16 MFMA)
__global__ void gemm_out(const bf16* __restrict__ A, const bf16* __restrict__ B,
                         const float* __restrict__ bias, float* __restrict__ C) {
    const int K = 1024, N = 1024;
    __shared__ bf16 smem[16384];
    bf16* A0 = smem;
    bf16* B0 = smem + 4096;
    bf16* A1 = smem + 8192;
    bf16* B1 = smem + 12288;
    int t = threadIdx.x;
    int lane = t & 63;
    int wave = t >> 6;
    int wm = wave >> 1, wn = wave & 1;
    int r = lane & 15, q = lane >> 4;
    int lin = blockIdx.x;
    int xcd = lin & 7, rr_ = lin >> 3;
    int mi = xcd * 8 + (rr_ & 7);
    int ni = rr_ >> 3;
    long m0 = (long)mi * 128;
    long n0 = (long)ni * 128;
    const bf16* Ab = A + m0 * K;
    const bf16* Bb = B + n0 * K;

    f32x4 acc[4][4] = {};

    int srow = t >> 2;
    int scol = (t & 3) << 3;

    GEMM_MAIN_LOOP

#pragma unroll
    for (int ni4 = 0; ni4 < 4; ni4++) {
        int n = (int)n0 + wn * 64 + ni4 * 16 + r;
        float bn = bias[n];
#pragma unroll
        for (int mi4 = 0; mi4 < 4; mi4++) {
#pragma unroll
            for (int rr = 0; rr < 4; rr++) {
                long m = m0 + wm * 64 + mi4 * 16 + q * 4 + rr;
                C[m * N + n] = acc[mi4][ni4][rr] + bn;
            }
        }
    }
}

// ---------------------------------------------------------------- launch
extern "C" void kernel_launch(void* const* d_in, const int* in_sizes, int n_in,
                              void* d_out, int out_size, void* d_ws, size_t ws_size,
                              hipStream_t stream) {
    const float* x    = (const float*)d_in[0];
    const float* Wqkv = (const float*)d_in[1];
    const float* bqkv = (const float*)d_in[2];
    const float* Wo   = (const float*)d_in[3];
    const float* bo   = (const float*)d_in[4];
    float* out = (float*)d_out;

    char* ws = (char*)d_ws;
    bf16* Xb  = (bf16*)(ws + 0);
    bf16* Wqb = (bf16*)(ws + 16777216);
    bf16* Wob = (bf16*)(ws + 23068672);
    bf16* Qb  = (bf16*)(ws + 25165824);
    bf16* Kb  = (bf16*)(ws + 41943040);
    bf16* Vtb = (bf16*)(ws + 58720256);
    bf16* AOb = (bf16*)(ws + 75497472);

    cvt_all<<<12288, 256, 0, stream>>>(x, Wqkv, Wo, Xb, Wqb, Wob);

    gemm_qkv<<<1536, 256, 0, stream>>>(Xb, Wqb, bqkv, Qb, Kb, Vtb);
    attn_fwd<<<512, 512, 0, stream>>>(Qb, Kb, Vtb, AOb);
    gemm_out<<<512, 256, 0, stream>>>(AOb, Wob, bo, out);
}

// Round 18
// 189.025 us; speedup vs baseline: 1.0407x; 1.0169x over previous
//
#include <hip/hip_runtime.h>
#include <hip/hip_bf16.h>

using bf16 = __hip_bfloat16;
typedef __attribute__((ext_vector_type(8))) __bf16 bf16x8;
typedef __attribute__((ext_vector_type(4))) float f32x4;
typedef __attribute__((ext_vector_type(16))) float f32x16;
typedef __attribute__((ext_vector_type(4))) unsigned u32x4;

#define MFMA16(a, b, c) __builtin_amdgcn_mfma_f32_16x16x32_bf16((a), (b), (c), 0, 0, 0)
#define MFMA32(a, b, c) __builtin_amdgcn_mfma_f32_32x32x16_bf16((a), (b), (c), 0, 0, 0)

#define WAITV4 asm volatile("s_waitcnt vmcnt(4)" ::: "memory")
#define WAITV0 asm volatile("s_waitcnt vmcnt(0)" ::: "memory")
#define WAITL0 asm volatile("s_waitcnt lgkmcnt(0)" ::: "memory")
#define BAR    __builtin_amdgcn_s_barrier()
#define SCHED0 __builtin_amdgcn_sched_barrier(0)

static __device__ __forceinline__ void gload_lds16(const bf16* g, bf16* l) {
    __builtin_amdgcn_global_load_lds(
        (__attribute__((address_space(1))) void*)(bf16*)(g),
        (__attribute__((address_space(3))) void*)(l), 16, 0, 0);
}

static __device__ __forceinline__ unsigned cvtpk(float lo, float hi) {
    unsigned r;
    asm("v_cvt_pk_bf16_f32 %0, %1, %2" : "=v"(r) : "v"(lo), "v"(hi));
    return r;
}

// ---------------------------------------------------------------- convert (all 3 inputs, one launch, 4 float4/thread)
__global__ void cvt_all(const float* __restrict__ x, const float* __restrict__ wq,
                        const float* __restrict__ wo,
                        bf16* __restrict__ xb, bf16* __restrict__ wqb, bf16* __restrict__ wob) {
    int b = blockIdx.x;
    const float* src;
    bf16* dst;
    long base;
    if (b < 2048)      { src = x;  dst = xb;  base = (long)b * 1024; }
    else if (b < 2816) { src = wq; dst = wqb; base = (long)(b - 2048) * 1024; }
    else               { src = wo; dst = wob; base = (long)(b - 2816) * 1024; }
#pragma unroll
    for (int c = 0; c < 4; ++c) {
        long i = base + c * 256 + threadIdx.x;
        float4 v = ((const float4*)src)[i];
        bf16 t[4];
        t[0] = __float2bfloat16(v.x);
        t[1] = __float2bfloat16(v.y);
        t[2] = __float2bfloat16(v.z);
        t[3] = __float2bfloat16(v.w);
        *(uint2*)(dst + 4l * i) = *(uint2*)t;
    }
}

// ---------------------------------------------------------------- shared GEMM pieces (16x16 MFMA, proven)
#define GEMM_STAGE(AB, BB, K0)                                             \
    do {                                                                   \
        gload_lds16(Ab + (long)srow * K + (K0) + scol, (AB) + t * 8);      \
        gload_lds16(Ab + (long)(srow + 64) * K + (K0) + scol, (AB) + 2048 + t * 8); \
        gload_lds16(Bb + (long)srow * K + (K0) + scol, (BB) + t * 8);      \
        gload_lds16(Bb + (long)(srow + 64) * K + (K0) + scol, (BB) + 2048 + t * 8); \
    } while (0)

#define GEMM_COMPUTE(AB, BB)                                               \
    do {                                                                   \
        bf16x8 af[4], bfv[4];                                              \
        _Pragma("unroll") for (int mi4 = 0; mi4 < 4; mi4++)                \
            af[mi4] = *(const bf16x8*)((AB) + (wm * 64 + mi4 * 16 + r) * 32 + q * 8); \
        _Pragma("unroll") for (int ni4 = 0; ni4 < 4; ni4++)                \
            bfv[ni4] = *(const bf16x8*)((BB) + (wn * 64 + ni4 * 16 + r) * 32 + q * 8); \
        __builtin_amdgcn_s_setprio(1);                                     \
        _Pragma("unroll") for (int mi4 = 0; mi4 < 4; mi4++)                \
            _Pragma("unroll") for (int ni4 = 0; ni4 < 4; ni4++)            \
                acc[mi4][ni4] = MFMA16(af[mi4], bfv[ni4], acc[mi4][ni4]);  \
        __builtin_amdgcn_s_setprio(0);                                     \
    } while (0)

#define GEMM_MAIN_LOOP                                                     \
    GEMM_STAGE(A0, B0, 0);                                                 \
    GEMM_STAGE(A1, B1, 32);                                                \
    for (int k0 = 0; k0 < K - 64; k0 += 64) {                              \
        WAITV4; BAR; SCHED0;                                               \
        GEMM_COMPUTE(A0, B0);                                              \
        WAITL0; BAR; SCHED0;                                               \
        GEMM_STAGE(A0, B0, k0 + 64);                                       \
        WAITV4; BAR; SCHED0;                                               \
        GEMM_COMPUTE(A1, B1);                                              \
        WAITL0; BAR; SCHED0;                                               \
        if (k0 + 96 < K) GEMM_STAGE(A1, B1, k0 + 96);                      \
    }                                                                      \
    WAITV4; BAR; SCHED0;                                                   \
    GEMM_COMPUTE(A0, B0);                                                  \
    WAITV0; BAR; SCHED0;                                                   \
    GEMM_COMPUTE(A1, B1);

// ---------------------------------------------------------------- GEMM1: qkv = x @ Wqkv^T + b, scatter to Q,K,V^T
__global__ void gemm_qkv(const bf16* __restrict__ A, const bf16* __restrict__ B,
                         const float* __restrict__ bias,
                         bf16* __restrict__ Qo, bf16* __restrict__ Ko, bf16* __restrict__ Vt) {
    const int K = 1024;
    __shared__ bf16 smem[16384];
    bf16* A0 = smem;
    bf16* B0 = smem + 4096;
    bf16* A1 = smem + 8192;
    bf16* B1 = smem + 12288;
    int t = threadIdx.x;
    int lane = t & 63;
    int wave = t >> 6;
    int wm = wave >> 1, wn = wave & 1;
    int r = lane & 15, q = lane >> 4;
    int lin = blockIdx.x;
    int xcd = lin & 7, rr_ = lin >> 3;
    int mi = xcd * 8 + (rr_ & 7);
    int ni = rr_ >> 3;
    long m0 = (long)mi * 128;
    long n0 = (long)ni * 128;
    const bf16* Ab = A + m0 * K;
    const bf16* Bb = B + n0 * K;

    f32x4 acc[4][4] = {};

    int srow = t >> 2;
    int scol = (t & 3) << 3;

    GEMM_MAIN_LOOP

    // ---- epilogue (Q/K direct; V via LDS transpose -> coalesced V^T rows)
    __syncthreads();
    bf16* vbuf = smem;
    int g64 = 2 * ni + wn;
    int pw = g64 % 3;
    int hw = g64 / 3;
#pragma unroll
    for (int ni4 = 0; ni4 < 4; ni4++) {
        int d = ni4 * 16 + r;
        float bn = bias[(int)n0 + wn * 64 + d];
#pragma unroll
        for (int mi4 = 0; mi4 < 4; mi4++) {
#pragma unroll
            for (int rr = 0; rr < 4; rr++) {
                int ml = wm * 64 + mi4 * 16 + q * 4 + rr;
                int m = (int)m0 + ml;
                bf16 bv = __float2bfloat16(acc[mi4][ni4][rr] + bn);
                if (pw == 0) {
                    int b = m >> 11; int row = m & 2047;
                    Qo[(((long)b * 16 + hw) * 2048 + row) * 64 + d] = bv;
                } else if (pw == 1) {
                    int b = m >> 11; int row = m & 2047;
                    Ko[(((long)b * 16 + hw) * 2048 + row) * 64 + d] = bv;
                } else {
                    vbuf[d * 136 + ml] = bv;
                }
            }
        }
    }
    __syncthreads();
    int vseg = ((2 * ni) % 3 == 2) ? 0 : (((2 * ni + 1) % 3 == 2) ? 1 : -1);
    if (vseg >= 0) {
        int hv = (2 * ni + vseg) / 3;
        int b = (int)(m0 >> 11);
        int row0 = (int)(m0 & 2047);
        long base = ((long)b * 16 + hv) * 64 * 2048;
#pragma unroll
        for (int c = 0; c < 4; ++c) {
            int u = c * 256 + t;
            int d = u >> 4;
            int ch = u & 15;
            int4 v = *(const int4*)(vbuf + d * 136 + ch * 8);
            *(int4*)(Vt + base + (long)d * 2048 + row0 + ch * 8) = v;
        }
    }
}

// ---------------------------------------------------------------- attention (round-9 proven config; max3 tree)
// 8 waves x 32 q = 256 q/block; KVBLK=64 double-buffered via global_load_lds.
// Swapped QK^T, in-register P (permlane32_swap), O^T accum, defer-max.

#define PACK8(S, OFF, OUTV) { \
    unsigned A0_ = cvtpk(S[OFF+0], S[OFF+1]); \
    unsigned B0_ = cvtpk(S[OFF+4], S[OFF+5]); \
    unsigned A1_ = cvtpk(S[OFF+2], S[OFF+3]); \
    unsigned B1_ = cvtpk(S[OFF+6], S[OFF+7]); \
    asm("v_permlane32_swap_b32 %0, %1" : "+v"(A0_), "+v"(B0_)); \
    asm("v_permlane32_swap_b32 %0, %1" : "+v"(A1_), "+v"(B1_)); \
    u32x4 W; W.x = A0_; W.y = A1_; W.z = B0_; W.w = B1_; \
    OUTV = __builtin_bit_cast(bf16x8, W); }

// balanced max of 16 via v_max3-fusable triples
#define MAX16(S, OUT) { \
    float u0 = fmaxf(fmaxf(S[0], S[1]), S[2]); \
    float u1 = fmaxf(fmaxf(S[3], S[4]), S[5]); \
    float u2 = fmaxf(fmaxf(S[6], S[7]), S[8]); \
    float u3 = fmaxf(fmaxf(S[9], S[10]), S[11]); \
    float u4 = fmaxf(fmaxf(S[12], S[13]), S[14]); \
    OUT = fmaxf(fmaxf(fmaxf(u0, u1), S[15]), fmaxf(fmaxf(u2, u3), u4)); }

#define COMPUTE(KB, VB) do { \
    f32x16 sA = {}, sB = {}; \
    __builtin_amdgcn_s_setprio(1); \
    { \
        bf16x8 kA, kB; \
        kA = *(const bf16x8*)(KB + (0 * 64 + lane) * 8); \
        kB = *(const bf16x8*)(KB + (256 + 0 * 64 + lane) * 8); \
        sA = MFMA32(kA, qf0, sA);  sB = MFMA32(kB, qf0, sB); \
        kA = *(const bf16x8*)(KB + (1 * 64 + lane) * 8); \
        kB = *(const bf16x8*)(KB + (256 + 1 * 64 + lane) * 8); \
        sA = MFMA32(kA, qf1, sA);  sB = MFMA32(kB, qf1, sB); \
        kA = *(const bf16x8*)(KB + (2 * 64 + lane) * 8); \
        kB = *(const bf16x8*)(KB + (256 + 2 * 64 + lane) * 8); \
        sA = MFMA32(kA, qf2, sA);  sB = MFMA32(kB, qf2, sB); \
        kA = *(const bf16x8*)(KB + (3 * 64 + lane) * 8); \
        kB = *(const bf16x8*)(KB + (256 + 3 * 64 + lane) * 8); \
        sA = MFMA32(kA, qf3, sA);  sB = MFMA32(kB, qf3, sB); \
    } \
    __builtin_amdgcn_s_setprio(0); \
    float pmA, pmB; \
    MAX16(sA, pmA); \
    MAX16(sB, pmB); \
    float pm = fmaxf(pmA, pmB); \
    pm = fmaxf(pm, __shfl_xor(pm, 32)); \
    bool resc = !__all(pm <= mv + 8.0f); \
    if (resc) { \
        float mn = fmaxf(mv, pm); \
        float al = __builtin_amdgcn_exp2f((mv - mn) * C1); \
        mv = mn; \
        lv *= al; \
        _Pragma("unroll") for (int e = 0; e < 16; ++e) { o0[e] *= al; o1[e] *= al; } \
    } \
    float mc = mv * C1; \
    float ts = 0.f; \
    _Pragma("unroll") for (int e = 0; e < 16; ++e) { float p = __builtin_amdgcn_exp2f(sA[e] * C1 - mc); sA[e] = p; ts += p; } \
    _Pragma("unroll") for (int e = 0; e < 16; ++e) { float p = __builtin_amdgcn_exp2f(sB[e] * C1 - mc); sB[e] = p; ts += p; } \
    ts += __shfl_xor(ts, 32); \
    lv += ts; \
    bf16x8 pf0, pf1, pf2, pf3; \
    PACK8(sA, 0, pf0); PACK8(sA, 8, pf1); PACK8(sB, 0, pf2); PACK8(sB, 8, pf3); \
    __builtin_amdgcn_s_setprio(1); \
    { \
        bf16x8 vA, vB; \
        vA = *(const bf16x8*)(VB + (0 * 64 + lane) * 8); \
        vB = *(const bf16x8*)(VB + (256 + 0 * 64 + lane) * 8); \
        o0 = MFMA32(vA, pf0, o0);  o1 = MFMA32(vB, pf0, o1); \
        vA = *(const bf16x8*)(VB + (1 * 64 + lane) * 8); \
        vB = *(const bf16x8*)(VB + (256 + 1 * 64 + lane) * 8); \
        o0 = MFMA32(vA, pf1, o0);  o1 = MFMA32(vB, pf1, o1); \
        vA = *(const bf16x8*)(VB + (2 * 64 + lane) * 8); \
        vB = *(const bf16x8*)(VB + (256 + 2 * 64 + lane) * 8); \
        o0 = MFMA32(vA, pf2, o0);  o1 = MFMA32(vB, pf2, o1); \
        vA = *(const bf16x8*)(VB + (3 * 64 + lane) * 8); \
        vB = *(const bf16x8*)(VB + (256 + 3 * 64 + lane) * 8); \
        o0 = MFMA32(vA, pf3, o0);  o1 = MFMA32(vB, pf3, o1); \
    } \
    __builtin_amdgcn_s_setprio(0); \
} while (0)

__global__ __launch_bounds__(512, 4) void attn_fwd(const bf16* __restrict__ Q,
                                                   const bf16* __restrict__ Kg,
                                                   const bf16* __restrict__ Vt,
                                                   bf16* __restrict__ AO) {
    __shared__ bf16 smem[16384];   // [K0 4096][V0 4096][K1 4096][V1 4096]
    bf16* K0 = smem;
    bf16* V0 = smem + 4096;
    bf16* K1 = smem + 8192;
    bf16* V1 = smem + 12288;
    const int t = threadIdx.x;
    const int lane = t & 63, wave = t >> 6;
    const int l31 = lane & 31, hi = lane >> 5;
    const int bid = blockIdx.x;
    const int xcd = bid & 7, idx = bid >> 3;
    const int bh = xcd * 8 + (idx >> 3);
    const int qt = idx & 7;
    const float C1 = 0.18033688011112042f;   // log2(e)/sqrt(64)

    bf16x8 qf0, qf1, qf2, qf3;
    {
        const bf16* Qb = Q + ((long)bh * 2048 + qt * 256 + wave * 32 + l31) * 64 + hi * 8;
        qf0 = *(const bf16x8*)(Qb + 0);
        qf1 = *(const bf16x8*)(Qb + 16);
        qf2 = *(const bf16x8*)(Qb + 32);
        qf3 = *(const bf16x8*)(Qb + 48);
    }

    const bf16* Kh = Kg + (long)bh * 2048 * 64;
    const bf16* Vh = Vt + (long)bh * 64 * 2048;

    const int sr = ((t >> 8) << 5) + (t & 31);
    const int sc = ((t >> 6) & 3) * 16 + ((t >> 5) & 1) * 8;

    f32x16 o0 = {}, o1 = {};
    float mv = -1e30f, lv = 0.f;

    auto issue_stage = [&](bf16* Kb, bf16* Vb, int kv0) {
        gload_lds16(Kh + (long)(kv0 + sr) * 64 + sc, Kb + t * 8);
        gload_lds16(Vh + (long)sr * 2048 + kv0 + sc, Vb + t * 8);
    };

    issue_stage(K0, V0, 0);
    __syncthreads();

    for (int kv0 = 0;; kv0 += 128) {
        issue_stage(K1, V1, kv0 + 64);
        COMPUTE(K0, V0);
        __syncthreads();
        if (kv0 + 128 < 2048) issue_stage(K0, V0, kv0 + 128);
        COMPUTE(K1, V1);
        if (kv0 + 128 >= 2048) break;
        __syncthreads();
    }

    // ---- epilogue: O^T -> LDS transpose -> coalesced global stores
    long bb = bh >> 4, hh = bh & 15;
    __syncthreads();
    float il = 1.f / lv;
    char* wbase = (char*)smem + wave * 4096 + l31 * 128;
#pragma unroll
    for (int j = 0; j < 4; ++j) {
        unsigned wlo = cvtpk(o0[4 * j] * il, o0[4 * j + 1] * il);
        unsigned whi = cvtpk(o0[4 * j + 2] * il, o0[4 * j + 3] * il);
        int b8 = 2 * j + hi;
        int b8s = b8 ^ ((l31 & 7) << 1);
        uint2 val; val.x = wlo; val.y = whi;
        *(uint2*)(wbase + b8s * 8) = val;
    }
#pragma unroll
    for (int j = 0; j < 4; ++j) {
        unsigned wlo = cvtpk(o1[4 * j] * il, o1[4 * j + 1] * il);
        unsigned whi = cvtpk(o1[4 * j + 2] * il, o1[4 * j + 3] * il);
        int b8 = 8 + 2 * j + hi;
        int b8s = b8 ^ ((l31 & 7) << 1);
        uint2 val; val.x = wlo; val.y = whi;
        *(uint2*)(wbase + b8s * 8) = val;
    }
    __syncthreads();
    {
        int rid = t >> 1, hf = t & 1;
        int wv = rid >> 5, qq = rid & 31;
        long orow = (long)qt * 256 + wv * 32 + qq;
        const char* rbase = (const char*)smem + wv * 4096 + qq * 128;
        bf16* dst = AO + (bb * 2048 + orow) * 1024 + hh * 64 + hf * 32;
#pragma unroll
        for (int k = 0; k < 4; ++k) {
            int b8 = hf * 8 + 2 * k;
            int b8s = b8 ^ ((qq & 7) << 1);
            int4 v = *(const int4*)(rbase + b8s * 8);
            *(int4*)(dst + k * 8) = v;
        }
    }
}

// ---------------------------------------------------------------- GEMM2: out = AO @ Wo^T + bo (fp32 out, 16x16 MFMA)
__global__ void gemm_out(const bf16* __restrict__ A, const bf16* __restrict__ B,
                         const float* __restrict__ bias, float* __restrict__ C) {
    const int K = 1024, N = 1024;
    __shared__ bf16 smem[16384];
    bf16* A0 = smem;
    bf16* B0 = smem + 4096;
    bf16* A1 = smem + 8192;
    bf16* B1 = smem + 12288;
    int t = threadIdx.x;
    int lane = t & 63;
    int wave = t >> 6;
    int wm = wave >> 1, wn = wave & 1;
    int r = lane & 15, q = lane >> 4;
    int lin = blockIdx.x;
    int xcd = lin & 7, rr_ = lin >> 3;
    int mi = xcd * 8 + (rr_ & 7);
    int ni = rr_ >> 3;
    long m0 = (long)mi * 128;
    long n0 = (long)ni * 128;
    const bf16* Ab = A + m0 * K;
    const bf16* Bb = B + n0 * K;

    f32x4 acc[4][4] = {};

    int srow = t >> 2;
    int scol = (t & 3) << 3;

    GEMM_MAIN_LOOP

#pragma unroll
    for (int ni4 = 0; ni4 < 4; ni4++) {
        int n = (int)n0 + wn * 64 + ni4 * 16 + r;
        float bn = bias[n];
#pragma unroll
        for (int mi4 = 0; mi4 < 4; mi4++) {
#pragma unroll
            for (int rr = 0; rr < 4; rr++) {
                long m = m0 + wm * 64 + mi4 * 16 + q * 4 + rr;
                C[m * N + n] = acc[mi4][ni4][rr] + bn;
            }
        }
    }
}

// ---------------------------------------------------------------- launch
extern "C" void kernel_launch(void* const* d_in, const int* in_sizes, int n_in,
                              void* d_out, int out_size, void* d_ws, size_t ws_size,
                              hipStream_t stream) {
    const float* x    = (const float*)d_in[0];
    const float* Wqkv = (const float*)d_in[1];
    const float* bqkv = (const float*)d_in[2];
    const float* Wo   = (const float*)d_in[3];
    const float* bo   = (const float*)d_in[4];
    float* out = (float*)d_out;

    char* ws = (char*)d_ws;
    bf16* Xb  = (bf16*)(ws + 0);
    bf16* Wqb = (bf16*)(ws + 16777216);
    bf16* Wob = (bf16*)(ws + 23068672);
    bf16* Qb  = (bf16*)(ws + 25165824);
    bf16* Kb  = (bf16*)(ws + 41943040);
    bf16* Vtb = (bf16*)(ws + 58720256);
    bf16* AOb = (bf16*)(ws + 75497472);

    cvt_all<<<3072, 256, 0, stream>>>(x, Wqkv, Wo, Xb, Wqb, Wob);

    gemm_qkv<<<1536, 256, 0, stream>>>(Xb, Wqb, bqkv, Qb, Kb, Vtb);
    attn_fwd<<<512, 512, 0, stream>>>(Qb, Kb, Vtb, AOb);
    gemm_out<<<512, 256, 0, stream>>>(AOb, Wob, bo, out);
}

// Round 19
// 188.308 us; speedup vs baseline: 1.0446x; 1.0038x over previous
//
#include <hip/hip_runtime.h>
#include <hip/hip_bf16.h>

using bf16 = __hip_bfloat16;
typedef __attribute__((ext_vector_type(8))) __bf16 bf16x8;
typedef __attribute__((ext_vector_type(4))) float f32x4;
typedef __attribute__((ext_vector_type(16))) float f32x16;
typedef __attribute__((ext_vector_type(4))) unsigned u32x4;

#define MFMA16(a, b, c) __builtin_amdgcn_mfma_f32_16x16x32_bf16((a), (b), (c), 0, 0, 0)
#define MFMA32(a, b, c) __builtin_amdgcn_mfma_f32_32x32x16_bf16((a), (b), (c), 0, 0, 0)

#define WAITV4 asm volatile("s_waitcnt vmcnt(4)" ::: "memory")
#define WAITV0 asm volatile("s_waitcnt vmcnt(0)" ::: "memory")
#define WAITL0 asm volatile("s_waitcnt lgkmcnt(0)" ::: "memory")
#define BAR    __builtin_amdgcn_s_barrier()
#define SCHED0 __builtin_amdgcn_sched_barrier(0)

static __device__ __forceinline__ void gload_lds16(const bf16* g, bf16* l) {
    __builtin_amdgcn_global_load_lds(
        (__attribute__((address_space(1))) void*)(bf16*)(g),
        (__attribute__((address_space(3))) void*)(l), 16, 0, 0);
}

static __device__ __forceinline__ unsigned cvtpk(float lo, float hi) {
    unsigned r;
    asm("v_cvt_pk_bf16_f32 %0, %1, %2" : "=v"(r) : "v"(lo), "v"(hi));
    return r;
}

// ---------------------------------------------------------------- convert (all 3 inputs, one launch, 4 float4/thread)
__global__ void cvt_all(const float* __restrict__ x, const float* __restrict__ wq,
                        const float* __restrict__ wo,
                        bf16* __restrict__ xb, bf16* __restrict__ wqb, bf16* __restrict__ wob) {
    int b = blockIdx.x;
    const float* src;
    bf16* dst;
    long base;
    if (b < 2048)      { src = x;  dst = xb;  base = (long)b * 1024; }
    else if (b < 2816) { src = wq; dst = wqb; base = (long)(b - 2048) * 1024; }
    else               { src = wo; dst = wob; base = (long)(b - 2816) * 1024; }
#pragma unroll
    for (int c = 0; c < 4; ++c) {
        long i = base + c * 256 + threadIdx.x;
        float4 v = ((const float4*)src)[i];
        bf16 t[4];
        t[0] = __float2bfloat16(v.x);
        t[1] = __float2bfloat16(v.y);
        t[2] = __float2bfloat16(v.z);
        t[3] = __float2bfloat16(v.w);
        *(uint2*)(dst + 4l * i) = *(uint2*)t;
    }
}

// ---------------------------------------------------------------- shared GEMM pieces (16x16 MFMA, proven)
#define GEMM_STAGE(AB, BB, K0)                                             \
    do {                                                                   \
        gload_lds16(Ab + (long)srow * K + (K0) + scol, (AB) + t * 8);      \
        gload_lds16(Ab + (long)(srow + 64) * K + (K0) + scol, (AB) + 2048 + t * 8); \
        gload_lds16(Bb + (long)srow * K + (K0) + scol, (BB) + t * 8);      \
        gload_lds16(Bb + (long)(srow + 64) * K + (K0) + scol, (BB) + 2048 + t * 8); \
    } while (0)

#define GEMM_COMPUTE(AB, BB)                                               \
    do {                                                                   \
        bf16x8 af[4], bfv[4];                                              \
        _Pragma("unroll") for (int mi4 = 0; mi4 < 4; mi4++)                \
            af[mi4] = *(const bf16x8*)((AB) + (wm * 64 + mi4 * 16 + r) * 32 + q * 8); \
        _Pragma("unroll") for (int ni4 = 0; ni4 < 4; ni4++)                \
            bfv[ni4] = *(const bf16x8*)((BB) + (wn * 64 + ni4 * 16 + r) * 32 + q * 8); \
        __builtin_amdgcn_s_setprio(1);                                     \
        _Pragma("unroll") for (int mi4 = 0; mi4 < 4; mi4++)                \
            _Pragma("unroll") for (int ni4 = 0; ni4 < 4; ni4++)            \
                acc[mi4][ni4] = MFMA16(af[mi4], bfv[ni4], acc[mi4][ni4]);  \
        __builtin_amdgcn_s_setprio(0);                                     \
    } while (0)

#define GEMM_MAIN_LOOP                                                     \
    GEMM_STAGE(A0, B0, 0);                                                 \
    GEMM_STAGE(A1, B1, 32);                                                \
    for (int k0 = 0; k0 < K - 64; k0 += 64) {                              \
        WAITV4; BAR; SCHED0;                                               \
        GEMM_COMPUTE(A0, B0);                                              \
        WAITL0; BAR; SCHED0;                                               \
        GEMM_STAGE(A0, B0, k0 + 64);                                       \
        WAITV4; BAR; SCHED0;                                               \
        GEMM_COMPUTE(A1, B1);                                              \
        WAITL0; BAR; SCHED0;                                               \
        if (k0 + 96 < K) GEMM_STAGE(A1, B1, k0 + 96);                      \
    }                                                                      \
    WAITV4; BAR; SCHED0;                                                   \
    GEMM_COMPUTE(A0, B0);                                                  \
    WAITV0; BAR; SCHED0;                                                   \
    GEMM_COMPUTE(A1, B1);

// ---------------------------------------------------------------- GEMM1: qkv = x @ Wqkv^T + b, scatter to Q,K,V^T
__global__ void gemm_qkv(const bf16* __restrict__ A, const bf16* __restrict__ B,
                         const float* __restrict__ bias,
                         bf16* __restrict__ Qo, bf16* __restrict__ Ko, bf16* __restrict__ Vt) {
    const int K = 1024;
    __shared__ bf16 smem[16384];
    bf16* A0 = smem;
    bf16* B0 = smem + 4096;
    bf16* A1 = smem + 8192;
    bf16* B1 = smem + 12288;
    int t = threadIdx.x;
    int lane = t & 63;
    int wave = t >> 6;
    int wm = wave >> 1, wn = wave & 1;
    int r = lane & 15, q = lane >> 4;
    int lin = blockIdx.x;
    int xcd = lin & 7, rr_ = lin >> 3;
    int mi = xcd * 8 + (rr_ & 7);
    int ni = rr_ >> 3;
    long m0 = (long)mi * 128;
    long n0 = (long)ni * 128;
    const bf16* Ab = A + m0 * K;
    const bf16* Bb = B + n0 * K;

    f32x4 acc[4][4] = {};

    int srow = t >> 2;
    int scol = (t & 3) << 3;

    GEMM_MAIN_LOOP

    // ---- epilogue (Q/K direct; V via LDS transpose -> coalesced V^T rows)
    __syncthreads();
    bf16* vbuf = smem;
    int g64 = 2 * ni + wn;
    int pw = g64 % 3;
    int hw = g64 / 3;
#pragma unroll
    for (int ni4 = 0; ni4 < 4; ni4++) {
        int d = ni4 * 16 + r;
        float bn = bias[(int)n0 + wn * 64 + d];
#pragma unroll
        for (int mi4 = 0; mi4 < 4; mi4++) {
#pragma unroll
            for (int rr = 0; rr < 4; rr++) {
                int ml = wm * 64 + mi4 * 16 + q * 4 + rr;
                int m = (int)m0 + ml;
                bf16 bv = __float2bfloat16(acc[mi4][ni4][rr] + bn);
                if (pw == 0) {
                    int b = m >> 11; int row = m & 2047;
                    Qo[(((long)b * 16 + hw) * 2048 + row) * 64 + d] = bv;
                } else if (pw == 1) {
                    int b = m >> 11; int row = m & 2047;
                    Ko[(((long)b * 16 + hw) * 2048 + row) * 64 + d] = bv;
                } else {
                    vbuf[d * 136 + ml] = bv;
                }
            }
        }
    }
    __syncthreads();
    int vseg = ((2 * ni) % 3 == 2) ? 0 : (((2 * ni + 1) % 3 == 2) ? 1 : -1);
    if (vseg >= 0) {
        int hv = (2 * ni + vseg) / 3;
        int b = (int)(m0 >> 11);
        int row0 = (int)(m0 & 2047);
        long base = ((long)b * 16 + hv) * 64 * 2048;
#pragma unroll
        for (int c = 0; c < 4; ++c) {
            int u = c * 256 + t;
            int d = u >> 4;
            int ch = u & 15;
            int4 v = *(const int4*)(vbuf + d * 136 + ch * 8);
            *(int4*)(Vt + base + (long)d * 2048 + row0 + ch * 8) = v;
        }
    }
}

// ---------------------------------------------------------------- attention (r18 config + tree-sum)
// 8 waves x 32 q = 256 q/block; KVBLK=64 double-buffered via global_load_lds.
// Swapped QK^T, in-register P (permlane32_swap), O^T accum, defer-max, max3 tree.

#define PACK8(S, OFF, OUTV) { \
    unsigned A0_ = cvtpk(S[OFF+0], S[OFF+1]); \
    unsigned B0_ = cvtpk(S[OFF+4], S[OFF+5]); \
    unsigned A1_ = cvtpk(S[OFF+2], S[OFF+3]); \
    unsigned B1_ = cvtpk(S[OFF+6], S[OFF+7]); \
    asm("v_permlane32_swap_b32 %0, %1" : "+v"(A0_), "+v"(B0_)); \
    asm("v_permlane32_swap_b32 %0, %1" : "+v"(A1_), "+v"(B1_)); \
    u32x4 W; W.x = A0_; W.y = A1_; W.z = B0_; W.w = B1_; \
    OUTV = __builtin_bit_cast(bf16x8, W); }

#define MAX16(S, OUT) { \
    float u0 = fmaxf(fmaxf(S[0], S[1]), S[2]); \
    float u1 = fmaxf(fmaxf(S[3], S[4]), S[5]); \
    float u2 = fmaxf(fmaxf(S[6], S[7]), S[8]); \
    float u3 = fmaxf(fmaxf(S[9], S[10]), S[11]); \
    float u4 = fmaxf(fmaxf(S[12], S[13]), S[14]); \
    OUT = fmaxf(fmaxf(fmaxf(u0, u1), S[15]), fmaxf(fmaxf(u2, u3), u4)); }

#define COMPUTE(KB, VB) do { \
    f32x16 sA = {}, sB = {}; \
    __builtin_amdgcn_s_setprio(1); \
    { \
        bf16x8 kA, kB; \
        kA = *(const bf16x8*)(KB + (0 * 64 + lane) * 8); \
        kB = *(const bf16x8*)(KB + (256 + 0 * 64 + lane) * 8); \
        sA = MFMA32(kA, qf0, sA);  sB = MFMA32(kB, qf0, sB); \
        kA = *(const bf16x8*)(KB + (1 * 64 + lane) * 8); \
        kB = *(const bf16x8*)(KB + (256 + 1 * 64 + lane) * 8); \
        sA = MFMA32(kA, qf1, sA);  sB = MFMA32(kB, qf1, sB); \
        kA = *(const bf16x8*)(KB + (2 * 64 + lane) * 8); \
        kB = *(const bf16x8*)(KB + (256 + 2 * 64 + lane) * 8); \
        sA = MFMA32(kA, qf2, sA);  sB = MFMA32(kB, qf2, sB); \
        kA = *(const bf16x8*)(KB + (3 * 64 + lane) * 8); \
        kB = *(const bf16x8*)(KB + (256 + 3 * 64 + lane) * 8); \
        sA = MFMA32(kA, qf3, sA);  sB = MFMA32(kB, qf3, sB); \
    } \
    __builtin_amdgcn_s_setprio(0); \
    float pmA, pmB; \
    MAX16(sA, pmA); \
    MAX16(sB, pmB); \
    float pm = fmaxf(pmA, pmB); \
    pm = fmaxf(pm, __shfl_xor(pm, 32)); \
    bool resc = !__all(pm <= mv + 8.0f); \
    if (resc) { \
        float mn = fmaxf(mv, pm); \
        float al = __builtin_amdgcn_exp2f((mv - mn) * C1); \
        mv = mn; \
        lv *= al; \
        _Pragma("unroll") for (int e = 0; e < 16; ++e) { o0[e] *= al; o1[e] *= al; } \
    } \
    float mc = mv * C1; \
    _Pragma("unroll") for (int e = 0; e < 16; ++e) sA[e] = __builtin_amdgcn_exp2f(sA[e] * C1 - mc); \
    _Pragma("unroll") for (int e = 0; e < 16; ++e) sB[e] = __builtin_amdgcn_exp2f(sB[e] * C1 - mc); \
    { \
        f32x16 scv = sA + sB; \
        float u0 = (scv[0] + scv[1]) + (scv[2] + scv[3]); \
        float u1 = (scv[4] + scv[5]) + (scv[6] + scv[7]); \
        float u2 = (scv[8] + scv[9]) + (scv[10] + scv[11]); \
        float u3 = (scv[12] + scv[13]) + (scv[14] + scv[15]); \
        float ts = (u0 + u1) + (u2 + u3); \
        ts += __shfl_xor(ts, 32); \
        lv += ts; \
    } \
    bf16x8 pf0, pf1, pf2, pf3; \
    PACK8(sA, 0, pf0); PACK8(sA, 8, pf1); PACK8(sB, 0, pf2); PACK8(sB, 8, pf3); \
    __builtin_amdgcn_s_setprio(1); \
    { \
        bf16x8 vA, vB; \
        vA = *(const bf16x8*)(VB + (0 * 64 + lane) * 8); \
        vB = *(const bf16x8*)(VB + (256 + 0 * 64 + lane) * 8); \
        o0 = MFMA32(vA, pf0, o0);  o1 = MFMA32(vB, pf0, o1); \
        vA = *(const bf16x8*)(VB + (1 * 64 + lane) * 8); \
        vB = *(const bf16x8*)(VB + (256 + 1 * 64 + lane) * 8); \
        o0 = MFMA32(vA, pf1, o0);  o1 = MFMA32(vB, pf1, o1); \
        vA = *(const bf16x8*)(VB + (2 * 64 + lane) * 8); \
        vB = *(const bf16x8*)(VB + (256 + 2 * 64 + lane) * 8); \
        o0 = MFMA32(vA, pf2, o0);  o1 = MFMA32(vB, pf2, o1); \
        vA = *(const bf16x8*)(VB + (3 * 64 + lane) * 8); \
        vB = *(const bf16x8*)(VB + (256 + 3 * 64 + lane) * 8); \
        o0 = MFMA32(vA, pf3, o0);  o1 = MFMA32(vB, pf3, o1); \
    } \
    __builtin_amdgcn_s_setprio(0); \
} while (0)

__global__ __launch_bounds__(512, 4) void attn_fwd(const bf16* __restrict__ Q,
                                                   const bf16* __restrict__ Kg,
                                                   const bf16* __restrict__ Vt,
                                                   bf16* __restrict__ AO) {
    __shared__ bf16 smem[16384];   // [K0 4096][V0 4096][K1 4096][V1 4096]
    bf16* K0 = smem;
    bf16* V0 = smem + 4096;
    bf16* K1 = smem + 8192;
    bf16* V1 = smem + 12288;
    const int t = threadIdx.x;
    const int lane = t & 63, wave = t >> 6;
    const int l31 = lane & 31, hi = lane >> 5;
    const int bid = blockIdx.x;
    const int xcd = bid & 7, idx = bid >> 3;
    const int bh = xcd * 8 + (idx >> 3);
    const int qt = idx & 7;
    const float C1 = 0.18033688011112042f;   // log2(e)/sqrt(64)

    bf16x8 qf0, qf1, qf2, qf3;
    {
        const bf16* Qb = Q + ((long)bh * 2048 + qt * 256 + wave * 32 + l31) * 64 + hi * 8;
        qf0 = *(const bf16x8*)(Qb + 0);
        qf1 = *(const bf16x8*)(Qb + 16);
        qf2 = *(const bf16x8*)(Qb + 32);
        qf3 = *(const bf16x8*)(Qb + 48);
    }

    const bf16* Kh = Kg + (long)bh * 2048 * 64;
    const bf16* Vh = Vt + (long)bh * 64 * 2048;

    const int sr = ((t >> 8) << 5) + (t & 31);
    const int sc = ((t >> 6) & 3) * 16 + ((t >> 5) & 1) * 8;

    f32x16 o0 = {}, o1 = {};
    float mv = -1e30f, lv = 0.f;

    auto issue_stage = [&](bf16* Kb, bf16* Vb, int kv0) {
        gload_lds16(Kh + (long)(kv0 + sr) * 64 + sc, Kb + t * 8);
        gload_lds16(Vh + (long)sr * 2048 + kv0 + sc, Vb + t * 8);
    };

    issue_stage(K0, V0, 0);
    __syncthreads();

    for (int kv0 = 0;; kv0 += 128) {
        issue_stage(K1, V1, kv0 + 64);
        COMPUTE(K0, V0);
        __syncthreads();
        if (kv0 + 128 < 2048) issue_stage(K0, V0, kv0 + 128);
        COMPUTE(K1, V1);
        if (kv0 + 128 >= 2048) break;
        __syncthreads();
    }

    // ---- epilogue: O^T -> LDS transpose -> coalesced global stores
    long bb = bh >> 4, hh = bh & 15;
    __syncthreads();
    float il = 1.f / lv;
    char* wbase = (char*)smem + wave * 4096 + l31 * 128;
#pragma unroll
    for (int j = 0; j < 4; ++j) {
        unsigned wlo = cvtpk(o0[4 * j] * il, o0[4 * j + 1] * il);
        unsigned whi = cvtpk(o0[4 * j + 2] * il, o0[4 * j + 3] * il);
        int b8 = 2 * j + hi;
        int b8s = b8 ^ ((l31 & 7) << 1);
        uint2 val; val.x = wlo; val.y = whi;
        *(uint2*)(wbase + b8s * 8) = val;
    }
#pragma unroll
    for (int j = 0; j < 4; ++j) {
        unsigned wlo = cvtpk(o1[4 * j] * il, o1[4 * j + 1] * il);
        unsigned whi = cvtpk(o1[4 * j + 2] * il, o1[4 * j + 3] * il);
        int b8 = 8 + 2 * j + hi;
        int b8s = b8 ^ ((l31 & 7) << 1);
        uint2 val; val.x = wlo; val.y = whi;
        *(uint2*)(wbase + b8s * 8) = val;
    }
    __syncthreads();
    {
        int rid = t >> 1, hf = t & 1;
        int wv = rid >> 5, qq = rid & 31;
        long orow = (long)qt * 256 + wv * 32 + qq;
        const char* rbase = (const char*)smem + wv * 4096 + qq * 128;
        bf16* dst = AO + (bb * 2048 + orow) * 1024 + hh * 64 + hf * 32;
#pragma unroll
        for (int k = 0; k < 4; ++k) {
            int b8 = hf * 8 + 2 * k;
            int b8s = b8 ^ ((qq & 7) << 1);
            int4 v = *(const int4*)(rbase + b8s * 8);
            *(int4*)(dst + k * 8) = v;
        }
    }
}

// ---------------------------------------------------------------- GEMM2: out = AO @ Wo^T + bo (fp32 out, 16x16 MFMA)
__global__ void gemm_out(const bf16* __restrict__ A, const bf16* __restrict__ B,
                         const float* __restrict__ bias, float* __restrict__ C) {
    const int K = 1024, N = 1024;
    __shared__ bf16 smem[16384];
    bf16* A0 = smem;
    bf16* B0 = smem + 4096;
    bf16* A1 = smem + 8192;
    bf16* B1 = smem + 12288;
    int t = threadIdx.x;
    int lane = t & 63;
    int wave = t >> 6;
    int wm = wave >> 1, wn = wave & 1;
    int r = lane & 15, q = lane >> 4;
    int lin = blockIdx.x;
    int xcd = lin & 7, rr_ = lin >> 3;
    int mi = xcd * 8 + (rr_ & 7);
    int ni = rr_ >> 3;
    long m0 = (long)mi * 128;
    long n0 = (long)ni * 128;
    const bf16* Ab = A + m0 * K;
    const bf16* Bb = B + n0 * K;

    f32x4 acc[4][4] = {};

    int srow = t >> 2;
    int scol = (t & 3) << 3;

    GEMM_MAIN_LOOP

#pragma unroll
    for (int ni4 = 0; ni4 < 4; ni4++) {
        int n = (int)n0 + wn * 64 + ni4 * 16 + r;
        float bn = bias[n];
#pragma unroll
        for (int mi4 = 0; mi4 < 4; mi4++) {
#pragma unroll
            for (int rr = 0; rr < 4; rr++) {
                long m = m0 + wm * 64 + mi4 * 16 + q * 4 + rr;
                C[m * N + n] = acc[mi4][ni4][rr] + bn;
            }
        }
    }
}

// ---------------------------------------------------------------- launch
extern "C" void kernel_launch(void* const* d_in, const int* in_sizes, int n_in,
                              void* d_out, int out_size, void* d_ws, size_t ws_size,
                              hipStream_t stream) {
    const float* x    = (const float*)d_in[0];
    const float* Wqkv = (const float*)d_in[1];
    const float* bqkv = (const float*)d_in[2];
    const float* Wo   = (const float*)d_in[3];
    const float* bo   = (const float*)d_in[4];
    float* out = (float*)d_out;

    char* ws = (char*)d_ws;
    bf16* Xb  = (bf16*)(ws + 0);
    bf16* Wqb = (bf16*)(ws + 16777216);
    bf16* Wob = (bf16*)(ws + 23068672);
    bf16* Qb  = (bf16*)(ws + 25165824);
    bf16* Kb  = (bf16*)(ws + 41943040);
    bf16* Vtb = (bf16*)(ws + 58720256);
    bf16* AOb = (bf16*)(ws + 75497472);

    cvt_all<<<3072, 256, 0, stream>>>(x, Wqkv, Wo, Xb, Wqb, Wob);

    gemm_qkv<<<1536, 256, 0, stream>>>(Xb, Wqb, bqkv, Qb, Kb, Vtb);
    attn_fwd<<<512, 512, 0, stream>>>(Qb, Kb, Vtb, AOb);
    gemm_out<<<512, 256, 0, stream>>>(AOb, Wob, bo, out);
}